// Round 6
// baseline (27.186 us; speedup 1.0000x reference)
//
#include <hip/hip_runtime.h>

#define TT 2048
#define BB 4096
#define DROP_ROWS 11
#define NOUT (BB - DROP_ROWS)   /* 4085 output rows */
#define PERIOD 24
#define BLOCK 256
#define HALF 12
#define ROWS 4

// Raw barrier: drain LDS ops only (cross-wave LDS visibility), leave global
// loads/stores in flight across the barrier. __syncthreads() would emit
// s_waitcnt vmcnt(0) and kill the cross-row prefetch + store pipelining.
#define BARRIER() asm volatile("s_waitcnt lgkmcnt(0)\n\ts_barrier" ::: "memory")

__global__ __launch_bounds__(BLOCK) void seasonal_decomp_kernel(
    const float* __restrict__ x, float* __restrict__ out) {
  // buf overlays: cs[0..2048] (cumsum) then sout[0..6143] (packed output).
  __shared__ float buf[6144];
  __shared__ float pp2[3][264];        // +8 pad -> reducer reads conflict-free
  __shared__ float wt0[4], wt1[4];
  __shared__ float pmean[PERIOD];
  float* const cs = buf;
  float* const sout = buf;

  const int tid = threadIdx.x;
  const int lane = tid & 63;
  const int wave = tid >> 6;
  const int rbase = blockIdx.x * ROWS;

  // per-thread constants (invariant across rows)
  const int q0 = (512 * wave + lane) % 24;   // phase of this thread's j=0 element
  int mA, mB, mC;                            // phase-slot (p>>3) for groups A,B,C
  if (q0 < 8)       { mA = 0; mB = 2; mC = 1; }
  else if (q0 < 16) { mA = 1; mB = 0; mC = 2; }
  else              { mA = 2; mB = 1; mC = 0; }

  // initial prefetch of first row
  float4 v0, v1;
  if (rbase < NOUT) {
    const float4* rx = (const float4*)(x + (size_t)(rbase + DROP_ROWS) * TT);
    v0 = rx[tid];
    v1 = rx[tid + 256];
  }

  for (int r = 0; r < ROWS; ++r) {
    const int orow_i = rbase + r;
    const bool active = (orow_i < NOUT);     // uniform per block

    float s0 = 0.f, s1 = 0.f, i0 = 0.f, i1 = 0.f;
    if (active) {
      // ---- wave-level inclusive scan of per-thread chunk sums ----
      s0 = v0.x + v0.y + v0.z + v0.w;
      s1 = v1.x + v1.y + v1.z + v1.w;
      i0 = s0; i1 = s1;
      #pragma unroll
      for (int off = 1; off < 64; off <<= 1) {
        float t0 = __shfl_up(i0, off, 64);
        float t1 = __shfl_up(i1, off, 64);
        if (lane >= off) { i0 += t0; i1 += t1; }
      }
      if (lane == 63) { wt0[wave] = i0; wt1[wave] = i1; }
    }
    BARRIER();                               // A1: wt ready; prev row LDS done

    if (active) {
      float W0 = 0.f, W1 = 0.f, H = 0.f;
      #pragma unroll
      for (int w = 0; w < 4; ++w) {
        float a = wt0[w], b = wt1[w];
        H += a;
        if (w < wave) { W0 += a; W1 += b; }
      }
      const float P0 = W0 + (i0 - s0);       // cs[4*tid]
      const float P1 = H + W1 + (i1 - s1);   // cs[1024 + 4*tid]
      float4 c0, c1;
      c0.x = P0; c0.y = P0 + v0.x; c0.z = c0.y + v0.y; c0.w = c0.z + v0.z;
      c1.x = P1; c1.y = P1 + v1.x; c1.z = c1.y + v1.y; c1.w = c1.z + v1.z;
      ((float4*)cs)[tid] = c0;
      ((float4*)cs)[tid + 256] = c1;
      if (tid == 255) cs[TT] = P1 + s1;
    }

    // ---- prefetch NEXT row; now ACTUALLY flies across the raw barriers ----
    if (r + 1 < ROWS && rbase + r + 1 < NOUT) {
      const float4* rx =
          (const float4*)(x + (size_t)(rbase + r + 1 + DROP_ROWS) * TT);
      v0 = rx[tid];
      v1 = rx[tid + 256];
    }
    BARRIER();                               // A2: cs ready (lgkm only)

    float tr[8], sdr[8];
    if (active) {
      // ---- trend + detrended; per-wave chunk t = 512*wave + 64*j + lane ----
      float A = 0.f, B = 0.f, C2 = 0.f;
      #pragma unroll
      for (int j = 0; j < 8; ++j) {
        const int t = 512 * wave + 64 * j + lane;
        const float xt = cs[t + 1] - cs[t];
        float trv;
        if (t >= HALF && t < TT - HALF - 1) {          // interior: count 25
          trv = (cs[t + HALF + 1] - cs[t - HALF]) * (1.0f / 25.0f);
        } else {
          const int a = (t - HALF < 0) ? 0 : t - HALF;
          const int e = (t + HALF + 1 > TT) ? TT : t + HALF + 1;
          trv = (cs[e] - cs[a]) / (float)(e - a);
        }
        tr[j] = trv;
        sdr[j] = xt - trv;
        if (j % 3 == 0) A += sdr[j];        // phase q0
        else if (j % 3 == 1) B += sdr[j];   // phase (q0+16)%24
        else C2 += sdr[j];                  // phase (q0+8)%24
      }
      pp2[mA][tid] = A;
      pp2[mB][tid] = B;
      pp2[mC][tid] = C2;
    }
    BARRIER();                               // C: pp2 ready (trend reads done)

    if (active && tid < PERIOD) {
      const int c = tid & 7, m = tid >> 3;   // phase = 8m + c
      float s = 0.f;
      #pragma unroll
      for (int k = 0; k < 32; ++k) s += pp2[m][8 * k + c];
      pmean[tid] = s * ((tid < 8) ? (1.0f / 86.f) : (1.0f / 85.f));
    }
    BARRIER();                               // D: pmean ready; cs dead

    if (active) {
      // ---- wave-local pack (stride-3 writes: 2 lanes/bank = free) ----
      float* const mysout = sout + 1536 * wave;
      int p = q0;
      #pragma unroll
      for (int j = 0; j < 8; ++j) {
        const int t64 = 64 * j + lane;
        const float pm = pmean[p];
        p += 16; if (p >= PERIOD) p -= PERIOD;
        mysout[3 * t64]     = tr[j];
        mysout[3 * t64 + 1] = pm;
        mysout[3 * t64 + 2] = sdr[j] - pm;
      }
      // ---- wave-local read-back + coalesced float4 stores (no barrier) ----
      const float4* so4 = (const float4*)mysout;
      float4* orow = (float4*)(out + (size_t)orow_i * (TT * 3));
      #pragma unroll
      for (int j = 0; j < 6; ++j)
        orow[384 * wave + 64 * j + lane] = so4[64 * j + lane];
    }
  }
}

extern "C" void kernel_launch(void* const* d_in, const int* in_sizes, int n_in,
                              void* d_out, int out_size, void* d_ws, size_t ws_size,
                              hipStream_t stream) {
  const float* x = (const float*)d_in[0];
  float* out = (float*)d_out;
  const int grid = (NOUT + ROWS - 1) / ROWS;   // 1022 blocks, ~4/CU, all resident
  seasonal_decomp_kernel<<<grid, BLOCK, 0, stream>>>(x, out);
}

// Round 8
// 26.885 us; speedup vs baseline: 1.0112x; 1.0112x over previous
//
#include <hip/hip_runtime.h>

#define TT 2048
#define BB 4096
#define DROP_ROWS 11
#define NOUT (BB - DROP_ROWS)   /* 4085 output rows */
#define PERIOD 24
#define BLOCK 256
#define HALF 12
#define ROWS 4

typedef float nfloat4 __attribute__((ext_vector_type(4)));

// Raw barrier: drain LDS ops only; leave global loads/stores in flight.
#define BARRIER() asm volatile("s_waitcnt lgkmcnt(0)\n\ts_barrier" ::: "memory")

__global__ __launch_bounds__(BLOCK) void seasonal_decomp_kernel(
    const float* __restrict__ x, float* __restrict__ out) {
  // buf overlays: cs[0..2048] (cumsum) then sout[0..6143] (packed output).
  __shared__ float buf[6144];
  __shared__ float pp2[3][264];        // +8 pad -> reducer reads conflict-free
  __shared__ float wt0[4], wt1[4];
  __shared__ float pmean[PERIOD];
  float* const cs = buf;
  float* const sout = buf;

  const int tid = threadIdx.x;
  const int lane = tid & 63;
  const int wave = tid >> 6;
  const int rbase = blockIdx.x * ROWS;

  // per-thread constants (invariant across rows)
  const int q0 = (512 * wave + lane) % 24;   // phase of this thread's j=0 element
  int mA, mB, mC;                            // phase-slot (p>>3) for groups A,B,C
  if (q0 < 8)       { mA = 0; mB = 2; mC = 1; }
  else if (q0 < 16) { mA = 1; mB = 0; mC = 2; }
  else              { mA = 2; mB = 1; mC = 0; }

  // initial prefetch of first row
  float4 v0, v1;
  if (rbase < NOUT) {
    const float4* rx = (const float4*)(x + (size_t)(rbase + DROP_ROWS) * TT);
    v0 = rx[tid];
    v1 = rx[tid + 256];
  }

  for (int r = 0; r < ROWS; ++r) {
    const int orow_i = rbase + r;
    const bool active = (orow_i < NOUT);     // uniform per block

    float s0 = 0.f, s1 = 0.f, i0 = 0.f, i1 = 0.f;
    if (active) {
      // ---- wave-level inclusive scan of per-thread chunk sums ----
      s0 = v0.x + v0.y + v0.z + v0.w;
      s1 = v1.x + v1.y + v1.z + v1.w;
      i0 = s0; i1 = s1;
      #pragma unroll
      for (int off = 1; off < 64; off <<= 1) {
        float t0 = __shfl_up(i0, off, 64);
        float t1 = __shfl_up(i1, off, 64);
        if (lane >= off) { i0 += t0; i1 += t1; }
      }
      if (lane == 63) { wt0[wave] = i0; wt1[wave] = i1; }
    }
    BARRIER();                               // A1: wt ready; prev row LDS done

    if (active) {
      float W0 = 0.f, W1 = 0.f, H = 0.f;
      #pragma unroll
      for (int w = 0; w < 4; ++w) {
        float a = wt0[w], b = wt1[w];
        H += a;
        if (w < wave) { W0 += a; W1 += b; }
      }
      const float P0 = W0 + (i0 - s0);       // cs[4*tid]
      const float P1 = H + W1 + (i1 - s1);   // cs[1024 + 4*tid]
      float4 c0, c1;
      c0.x = P0; c0.y = P0 + v0.x; c0.z = c0.y + v0.y; c0.w = c0.z + v0.z;
      c1.x = P1; c1.y = P1 + v1.x; c1.z = c1.y + v1.y; c1.w = c1.z + v1.z;
      ((float4*)cs)[tid] = c0;
      ((float4*)cs)[tid + 256] = c1;
      if (tid == 255) cs[TT] = P1 + s1;
    }

    // ---- prefetch NEXT row; flies across the lgkm-only barriers ----
    if (r + 1 < ROWS && rbase + r + 1 < NOUT) {
      const float4* rx =
          (const float4*)(x + (size_t)(rbase + r + 1 + DROP_ROWS) * TT);
      v0 = rx[tid];
      v1 = rx[tid + 256];
    }
    BARRIER();                               // A2: cs ready

    float tr[8], sdr[8];
    if (active) {
      // ---- trend + detrended; per-wave chunk t = 512*wave + 64*j + lane ----
      float A = 0.f, B = 0.f, C2 = 0.f;
      #pragma unroll
      for (int j = 0; j < 8; ++j) {
        const int t = 512 * wave + 64 * j + lane;
        const float xt = cs[t + 1] - cs[t];
        float trv;
        if (t >= HALF && t < TT - HALF - 1) {          // interior: count 25
          trv = (cs[t + HALF + 1] - cs[t - HALF]) * (1.0f / 25.0f);
        } else {
          const int a = (t - HALF < 0) ? 0 : t - HALF;
          const int e = (t + HALF + 1 > TT) ? TT : t + HALF + 1;
          trv = (cs[e] - cs[a]) / (float)(e - a);
        }
        tr[j] = trv;
        sdr[j] = xt - trv;
        if (j % 3 == 0) A += sdr[j];        // phase q0
        else if (j % 3 == 1) B += sdr[j];   // phase (q0+16)%24
        else C2 += sdr[j];                  // phase (q0+8)%24
      }
      pp2[mA][tid] = A;
      pp2[mB][tid] = B;
      pp2[mC][tid] = C2;
    }
    BARRIER();                               // C: pp2 ready

    if (active && tid < PERIOD) {
      const int c = tid & 7, m = tid >> 3;   // phase = 8m + c
      float s = 0.f;
      #pragma unroll
      for (int k = 0; k < 32; ++k) s += pp2[m][8 * k + c];
      pmean[tid] = s * ((tid < 8) ? (1.0f / 86.f) : (1.0f / 85.f));
    }
    BARRIER();                               // D: pmean ready; cs dead

    if (active) {
      // ---- wave-local pack (stride-3 writes: 2 lanes/bank = free) ----
      float* const mysout = sout + 1536 * wave;
      int p = q0;
      #pragma unroll
      for (int j = 0; j < 8; ++j) {
        const int t64 = 64 * j + lane;
        const float pm = pmean[p];
        p += 16; if (p >= PERIOD) p -= PERIOD;
        mysout[3 * t64]     = tr[j];
        mysout[3 * t64 + 1] = pm;
        mysout[3 * t64 + 2] = sdr[j] - pm;
      }
      // ---- wave-local read-back + coalesced NON-TEMPORAL float4 stores ----
      // Output has zero reuse: evict-first keeps the 33 MB input L3-resident
      // across graph replays instead of churning L2/L3 with 100 MB of writes.
      const nfloat4* so4 = (const nfloat4*)mysout;
      nfloat4* orow = (nfloat4*)(out + (size_t)orow_i * (TT * 3));
      #pragma unroll
      for (int j = 0; j < 6; ++j) {
        nfloat4 v = so4[64 * j + lane];
        __builtin_nontemporal_store(v, &orow[384 * wave + 64 * j + lane]);
      }
    }
  }
}

extern "C" void kernel_launch(void* const* d_in, const int* in_sizes, int n_in,
                              void* d_out, int out_size, void* d_ws, size_t ws_size,
                              hipStream_t stream) {
  const float* x = (const float*)d_in[0];
  float* out = (float*)d_out;
  const int grid = (NOUT + ROWS - 1) / ROWS;   // 1022 blocks, ~4/CU, all resident
  seasonal_decomp_kernel<<<grid, BLOCK, 0, stream>>>(x, out);
}